// Round 16
// baseline (125.607 us; speedup 1.0000x reference)
//
#include <hip/hip_runtime.h>
#include <stdint.h>

typedef __attribute__((ext_vector_type(8))) __bf16 bf16x8;
typedef __attribute__((ext_vector_type(4))) float f32x4;

__device__ __forceinline__ unsigned short f2bf(float f) {
  union { float f; unsigned int u; } v; v.f = f;
  unsigned int u = v.u;
  u = (u + 0x7FFFu + ((u >> 16) & 1u)) >> 16;   // RNE
  return (unsigned short)u;
}
__device__ __forceinline__ float bf2f(unsigned int u) {
  union { unsigned int u; float f; } v; v.u = u << 16;
  return v.f;
}

// ---------------------------------------------------------------------------
// Kernel 1 (prep): fused  [bid < 4096] x f32 -> bf16 flat copy
//                         [bid >= 4096] W transpose+convert into Wt3 concat.
// ---------------------------------------------------------------------------
__global__ __launch_bounds__(256) void prep(
    const float* __restrict__ x, unsigned short* __restrict__ xb,
    const float* __restrict__ Wa, const float* __restrict__ Wsh,
    const float* __restrict__ Wsc, unsigned short* __restrict__ Wt3)
{
  __shared__ float t[64][65];
  int bid = blockIdx.x;
  if (bid < 4096) {
    const size_t i = ((size_t)bid * 256 + threadIdx.x) * 8;
    const float4 a = *(const float4*)(x + i);
    const float4 b = *(const float4*)(x + i + 4);
    ushort4 o0, o1;
    o0.x = f2bf(a.x); o0.y = f2bf(a.y); o0.z = f2bf(a.z); o0.w = f2bf(a.w);
    o1.x = f2bf(b.x); o1.y = f2bf(b.y); o1.z = f2bf(b.z); o1.w = f2bf(b.w);
    *(ushort4*)(xb + i) = o0;
    *(ushort4*)(xb + i + 4) = o1;
    return;
  }
  bid -= 4096;                       // 768 blocks: 16 x 16 x 3
  const int z  = bid >> 8;           // mat
  const int yy = (bid >> 4) & 15;    // n tile
  const int xx = bid & 15;           // k tile
  const float* W = (z == 0) ? Wa : (z == 1) ? Wsh : Wsc;
  unsigned short* O = Wt3 + ((size_t)z << 20);
  const int k0 = xx * 64;
  const int n0 = yy * 64;
  const int r = threadIdx.x >> 4;
  const int c4 = threadIdx.x & 15;
#pragma unroll
  for (int i = 0; i < 4; ++i) {
    const int row = r + i * 16;
    const float4 v = *(const float4*)(W + (size_t)(k0 + row) * 1024 + n0 + c4 * 4);
    t[row][c4 * 4 + 0] = v.x; t[row][c4 * 4 + 1] = v.y;
    t[row][c4 * 4 + 2] = v.z; t[row][c4 * 4 + 3] = v.w;
  }
  __syncthreads();
#pragma unroll
  for (int i = 0; i < 4; ++i) {
    const int nr = r + i * 16;
    ushort4 o;
    o.x = f2bf(t[c4 * 4 + 0][nr]);
    o.y = f2bf(t[c4 * 4 + 1][nr]);
    o.z = f2bf(t[c4 * 4 + 2][nr]);
    o.w = f2bf(t[c4 * 4 + 3][nr]);
    *(ushort4*)(O + (size_t)(n0 + nr) * 1024 + k0 + c4 * 4) = o;
  }
}

// ---------------------------------------------------------------------------
// Kernel 2: fused triple GEMM + in-kernel Gaussian filter + combine.
// R15 post-mortem: 4 schedule variants (drain / counted depth-2 / depth-3 /
// phase-split) all ~70us GEMM -- the shared constraint is 8 barrier-synced
// waves at 1 block/CU: no independent work covers ds_read latency or the
// drain. m97's 874 TF point = 4-wave blocks x ~3 independent blocks/CU with
// a PLAIN 2-barrier loop (m114: cross-block overlap eats the barrier stall).
// That configuration was never run with the two proven wins (pure-gload_lds
// staging, fused filter epilogue).
// R16 = R12's loop verbatim, halved block: 256 thr / 4 waves (2Mx2N, wave
// 64x32x3mats, acc 96+16), BM=128(+16 halo) BN=64x3 BK=64, single-buffer
// LDS: staging 43008 B, epilogue union 54016 B -> 3 blocks/CU. Grid 1024
// (64Mx16N), XCD-ownership remap (R7). Swizzle swz(row)=(row&7)<<4 on
// gload_lds SOURCE + ds_read (rule #21). Only changed variable vs R12:
// independent blocks/CU 1 -> 3.
// ---------------------------------------------------------------------------
__global__ __launch_bounds__(256, 3) void gemm_all(
    const unsigned short* __restrict__ xb, const unsigned short* __restrict__ Wt3,
    const float* __restrict__ ba, const float* __restrict__ bsh,
    const float* __restrict__ bsc, float* __restrict__ out)
{
  // staging: sX rows 0..127 main @0 (16384 B), rows 128..143 halo @16384
  // (2048 B), sB @18432 (3 x 64 x 128 B = 24576) -> 43008 B.
  // epilogue union: ysh [64][146] @0 (18688), ysc @18688, aff [64][130]
  // @37376 (16640) -> 54016 B total (3 x 54272 <= 163840: 3 blocks/CU).
  __shared__ __attribute__((aligned(16))) char lds[54016];
  unsigned short* const sX = (unsigned short*)lds;
  unsigned short* const sB = (unsigned short*)(lds + 18432);
  unsigned short* const ysh_l = (unsigned short*)lds;
  unsigned short* const ysc_l = (unsigned short*)(lds + 18688);
  unsigned short* const aff_l = (unsigned short*)(lds + 37376);

  const int tid = threadIdx.x;
  const int lane = tid & 63;
  const int wid = tid >> 6;      // 0..3
  const int wm = wid >> 1;       // 0..1 (M half: 64 rows)
  const int wn = wid & 1;        // 0..1 (N half: 32 cols)
  const int lr = lane & 15;
  const int lk = lane >> 4;

  // 1024 blocks = 64 M x 16 N. XCD-ownership remap (R7-proven).
  const int bid = blockIdx.x;
  const int xcd = bid & 7;
  const int rr_ = bid >> 3;          // 0..127
  const int ntl = rr_ & 15;
  const int mg  = rr_ >> 4;          // 0..7
  const int bm0 = (xcd + (mg << 3)) * 128;
  const int bn0 = ntl * 64;
  const bool first = ((bm0 & 1023) == 0);   // batch boundary above this tile

  f32x4 acc[3][4][2];                // [mat][m][jj] = 96 regs
  f32x4 hacc[2][2];                  // halo rows (wm==0 waves): 16 regs
  const f32x4 z = {0.f, 0.f, 0.f, 0.f};
#pragma unroll
  for (int a = 0; a < 3; ++a)
#pragma unroll
    for (int m = 0; m < 4; ++m)
#pragma unroll
      for (int j = 0; j < 2; ++j) acc[a][m][j] = z;
#pragma unroll
  for (int a = 0; a < 2; ++a)
#pragma unroll
    for (int j = 0; j < 2; ++j) hacc[a][j] = z;

  // stage one K-tile (BK=64). LDS rows 0..127 = bm0+row, 128..143 = halo
  // (bm0-16..bm0-1; dummy row bm0 when first). Swizzle on global SOURCE.
  auto stage = [&](int k0) {
#pragma unroll
    for (int p = 0; p < 4; ++p) {                 // main X: 4 x 4 KB rounds
      const int po = (p * 256 + tid) * 16;
      const int row = po >> 7;                    // 0..127
      const int lo = po ^ ((row & 7) << 4);
      const int colu = (lo & 127) >> 1;
      const unsigned short* src = xb + (size_t)(bm0 + row) * 1024 + k0 + colu;
      __builtin_amdgcn_global_load_lds(
          (const __attribute__((address_space(1))) void*)src,
          (__attribute__((address_space(3))) void*)(sX + (p * 256 + (wid << 6)) * 8),
          16, 0, 0);
    }
    if (tid < 128) {                              // halo X: waves 0-1 only
      const int po = 16384 + tid * 16;
      const int row = po >> 7;                    // 128..143
      const int lo = po ^ ((row & 7) << 4);
      const int colu = (lo & 127) >> 1;
      int grow = bm0 - 16 + (row - 128);
      if (first) grow = bm0;                      // dummy; epilogue zeroes halo
      const unsigned short* src = xb + (size_t)grow * 1024 + k0 + colu;
      __builtin_amdgcn_global_load_lds(
          (const __attribute__((address_space(1))) void*)src,
          (__attribute__((address_space(3))) void*)(sX + 8192 + (wid << 6) * 8),
          16, 0, 0);
    }
#pragma unroll
    for (int mat = 0; mat < 3; ++mat)             // B: 3 mats x 2 rounds
#pragma unroll
      for (int p = 0; p < 2; ++p) {
        const int po = (p * 256 + tid) * 16;
        const int row = po >> 7;                  // 0..63
        const int lo = po ^ ((row & 7) << 4);
        const int colu = (lo & 127) >> 1;
        const unsigned short* src =
            Wt3 + ((size_t)mat << 20) + (size_t)(bn0 + row) * 1024 + k0 + colu;
        __builtin_amdgcn_global_load_lds(
            (const __attribute__((address_space(1))) void*)src,
            (__attribute__((address_space(3))) void*)(sB + mat * 4096 + (p * 256 + (wid << 6)) * 8),
            16, 0, 0);
      }
  };
  auto rd = [&](const unsigned short* base, int row, int s) -> bf16x8 {
    const int po = row * 128 + (((s * 32 + lk * 8) * 2) ^ ((row & 7) << 4));
    return *(const bf16x8*)((const char*)base + po);
  };

  stage(0);

  for (int kt = 0; kt < 16; ++kt) {
    __syncthreads();   // tile ready (drains vmcnt+lgkm); covered by co-blocks

#pragma unroll
    for (int s = 0; s < 2; ++s) {
      bf16x8 ax[4], bb[3][2], hax;
#pragma unroll
      for (int m = 0; m < 4; ++m)
        ax[m] = rd(sX, wm * 64 + m * 16 + lr, s);
#pragma unroll
      for (int mat = 0; mat < 3; ++mat)
#pragma unroll
        for (int jj = 0; jj < 2; ++jj)
          bb[mat][jj] = rd(sB + mat * 4096, wn * 32 + jj * 16 + lr, s);
      if (wm == 0) hax = rd(sX, 128 + lr, s);

      __builtin_amdgcn_s_setprio(1);
#pragma unroll
      for (int m = 0; m < 4; ++m)
#pragma unroll
        for (int mat = 0; mat < 3; ++mat)
#pragma unroll
          for (int jj = 0; jj < 2; ++jj)
            acc[mat][m][jj] = __builtin_amdgcn_mfma_f32_16x16x32_bf16(
                ax[m], bb[mat][jj], acc[mat][m][jj], 0, 0, 0);
      if (wm == 0) {
#pragma unroll
        for (int mat = 1; mat < 3; ++mat)
#pragma unroll
          for (int jj = 0; jj < 2; ++jj)
            hacc[mat - 1][jj] = __builtin_amdgcn_mfma_f32_16x16x32_bf16(
                hax, bb[mat][jj], hacc[mat - 1][jj], 0, 0, 0);
      }
      __builtin_amdgcn_s_setprio(0);
    }

    __syncthreads();   // all reads done; LDS reusable
    if (kt + 1 < 16) stage((kt + 1) * 64);
  }

  // ---- epilogue: dump acc -> LDS bf16, Gaussian filter along t, combine ----
  // C/D layout: col=lane&15, row=(lane>>4)*4+reg [m89/m91]
#pragma unroll
  for (int jj = 0; jj < 2; ++jj) {
    const int nn = wn * 32 + jj * 16 + lr;          // 0..63
    const float Ba = ba[bn0 + nn];
#pragma unroll
    for (int m = 0; m < 4; ++m)
#pragma unroll
      for (int q = 0; q < 4; ++q) {
        const int rowL = wm * 64 + m * 16 + lk * 4 + q;   // 0..127
        aff_l[nn * 130 + rowL] = f2bf(fmaxf(acc[0][m][jj][q] + Ba, 0.0f));
        ysh_l[nn * 146 + 15 + rowL] = f2bf(acc[1][m][jj][q]);
        ysc_l[nn * 146 + 15 + rowL] = f2bf(acc[2][m][jj][q]);
      }
    if (wm == 0) {
#pragma unroll
      for (int q = 0; q < 4; ++q) {
        const int hr = lk * 4 + q;          // 0..15 <-> global bm0-16+hr
        if (hr > 0) {                       // entries 0..14 = bm0-15..bm0-1
          ysh_l[nn * 146 + hr - 1] = f2bf(hacc[0][jj][q]);
          ysc_l[nn * 146 + hr - 1] = f2bf(hacc[1][jj][q]);
        }
      }
    }
  }
  __syncthreads();
  if (first) {     // batch start: halo is zeros
    for (int i = tid; i < 64 * 15; i += 256) {
      const int nn = i / 15, rw = i % 15;
      ysh_l[nn * 146 + rw] = 0;
      ysc_l[nn * 146 + rw] = 0;
    }
  }
  __syncthreads();

  // filter + combine: thread owns (col nn, 32 rows)
  {
    const int nn = tid & 63;
    const int t0 = (tid >> 6) * 32;                 // 0, 32, 64, 96
    float g[16];
#pragma unroll
    for (int k = 0; k < 16; ++k) g[k] = __expf(-(float)(k * k) * 0.125f);
    float nfull = 0.f;
#pragma unroll
    for (int k = 0; k < 16; ++k) nfull += g[k];
    const float invf = 1.0f / nfull;
    const float bs = bsh[bn0 + nn];
    const float bc = bsc[bn0 + nn];

    float psh[15], psc[15];
#pragma unroll
    for (int i = 0; i < 15; ++i) {                  // rows t0-15..t0-1
      psh[i] = bf2f(ysh_l[nn * 146 + t0 + i]);
      psc[i] = bf2f(ysc_l[nn * 146 + t0 + i]);
    }

    for (int c = 0; c < 2; ++c) {                   // 2 chunks of 16 rows
      const int T = t0 + c * 16;
      float csh[16], csc[16], av[16];
#pragma unroll
      for (int u = 0; u < 16; ++u) {
        csh[u] = bf2f(ysh_l[nn * 146 + 15 + T + u]);
        csc[u] = bf2f(ysc_l[nn * 146 + 15 + T + u]);
        av[u]  = bf2f(aff_l[nn * 130 + T + u]);
      }
#pragma unroll
      for (int u = 0; u < 16; ++u) {
        float fs = 0.f, fc = 0.f;
#pragma unroll
        for (int k = 0; k < 16; ++k) {
          const int d = u - k;
          const float vs = (d >= 0) ? csh[d] : psh[15 + d];
          const float vc = (d >= 0) ? csc[d] : psc[15 + d];
          fs = fmaf(g[k], vs, fs);
          fc = fmaf(g[k], vc, fc);
        }
        float inv = invf;
        if (first && (T + u) < 15) {                // partial norm, batch start
          float sum = 0.f;
#pragma unroll
          for (int k = 0; k < 16; ++k) sum += (k <= T + u) ? g[k] : 0.f;
          inv = 1.0f / sum;
        }
        out[(size_t)(bm0 + T + u) * 1024 + bn0 + nn] =
            (fc * inv + bc) * av[u] + (fs * inv + bs);
      }
#pragma unroll
      for (int i = 0; i < 15; ++i) { psh[i] = csh[i + 1]; psc[i] = csc[i + 1]; }
    }
  }
}

// ---------------------------------------------------------------------------
// Workspace layout (22 MiB, proven safe):
//   xb  : ws + 0        16 MiB (x as bf16)
//   Wt3 : ws + 16 MiB    6 MiB (concat Wa^T|Wshift^T|Wscale^T, bf16)
// d_out is written ONCE by gemm_all (final f32).
// ---------------------------------------------------------------------------
extern "C" void kernel_launch(void* const* d_in, const int* in_sizes, int n_in,
                              void* d_out, int out_size, void* d_ws, size_t ws_size,
                              hipStream_t stream) {
  const float* x   = (const float*)d_in[0];
  const float* Wa  = (const float*)d_in[1];
  const float* ba  = (const float*)d_in[2];
  const float* Wsh = (const float*)d_in[3];
  const float* bsh = (const float*)d_in[4];
  const float* Wsc = (const float*)d_in[5];
  const float* bsc = (const float*)d_in[6];
  float* out = (float*)d_out;

  char* ws = (char*)d_ws;
  unsigned short* xb  = (unsigned short*)(ws);
  unsigned short* Wt3 = (unsigned short*)(ws + (16u << 20));

  hipLaunchKernelGGL(prep, dim3(4096 + 768), dim3(256), 0, stream,
                     x, xb, Wa, Wsh, Wsc, Wt3);
  hipLaunchKernelGGL(gemm_all, dim3(1024), dim3(256), 0, stream,
                     xb, Wt3, ba, bsh, bsc, out);
}

// Round 17
// 79.454 us; speedup vs baseline: 1.5809x; 1.5809x over previous
//
#include <hip/hip_runtime.h>
#include <stdint.h>

typedef __attribute__((ext_vector_type(8))) __bf16 bf16x8;
typedef __attribute__((ext_vector_type(4))) float f32x4;

__device__ __forceinline__ unsigned short f2bf(float f) {
  union { float f; unsigned int u; } v; v.f = f;
  unsigned int u = v.u;
  u = (u + 0x7FFFu + ((u >> 16) & 1u)) >> 16;   // RNE
  return (unsigned short)u;
}
__device__ __forceinline__ float bf2f(unsigned int u) {
  union { unsigned int u; float f; } v; v.u = u << 16;
  return v.f;
}

// ---------------------------------------------------------------------------
// Kernel 1 (prep): fused  [bid < 4096] x f32 -> bf16 flat copy
//                         [bid >= 4096] W transpose+convert into Wt3 concat.
// ---------------------------------------------------------------------------
__global__ __launch_bounds__(256) void prep(
    const float* __restrict__ x, unsigned short* __restrict__ xb,
    const float* __restrict__ Wa, const float* __restrict__ Wsh,
    const float* __restrict__ Wsc, unsigned short* __restrict__ Wt3)
{
  __shared__ float t[64][65];
  int bid = blockIdx.x;
  if (bid < 4096) {
    const size_t i = ((size_t)bid * 256 + threadIdx.x) * 8;
    const float4 a = *(const float4*)(x + i);
    const float4 b = *(const float4*)(x + i + 4);
    ushort4 o0, o1;
    o0.x = f2bf(a.x); o0.y = f2bf(a.y); o0.z = f2bf(a.z); o0.w = f2bf(a.w);
    o1.x = f2bf(b.x); o1.y = f2bf(b.y); o1.z = f2bf(b.z); o1.w = f2bf(b.w);
    *(ushort4*)(xb + i) = o0;
    *(ushort4*)(xb + i + 4) = o1;
    return;
  }
  bid -= 4096;                       // 768 blocks: 16 x 16 x 3
  const int z  = bid >> 8;           // mat
  const int yy = (bid >> 4) & 15;    // n tile
  const int xx = bid & 15;           // k tile
  const float* W = (z == 0) ? Wa : (z == 1) ? Wsh : Wsc;
  unsigned short* O = Wt3 + ((size_t)z << 20);
  const int k0 = xx * 64;
  const int n0 = yy * 64;
  const int r = threadIdx.x >> 4;
  const int c4 = threadIdx.x & 15;
#pragma unroll
  for (int i = 0; i < 4; ++i) {
    const int row = r + i * 16;
    const float4 v = *(const float4*)(W + (size_t)(k0 + row) * 1024 + n0 + c4 * 4);
    t[row][c4 * 4 + 0] = v.x; t[row][c4 * 4 + 1] = v.y;
    t[row][c4 * 4 + 2] = v.z; t[row][c4 * 4 + 3] = v.w;
  }
  __syncthreads();
#pragma unroll
  for (int i = 0; i < 4; ++i) {
    const int nr = r + i * 16;
    ushort4 o;
    o.x = f2bf(t[c4 * 4 + 0][nr]);
    o.y = f2bf(t[c4 * 4 + 1][nr]);
    o.z = f2bf(t[c4 * 4 + 2][nr]);
    o.w = f2bf(t[c4 * 4 + 3][nr]);
    *(ushort4*)(O + (size_t)(n0 + nr) * 1024 + k0 + c4 * 4) = o;
  }
}

// ---------------------------------------------------------------------------
// Kernel 2: fused triple GEMM + in-kernel Gaussian filter + combine.
// FINAL (= R13, the measured best at 79.3 us total). Structure:
// - Both operands staged bf16 via global_load_lds (zero in-loop VALU) --
//   the R12 win that broke the 100-125 us plateau.
// - Depth-2 LDS ring with counted tile-boundary vmcnt (8|7 by wave class,
//   0 only on the last tile) + raw s_barrier pair per K-step.
// - Fused epilogue: acc -> LDS bf16, causal Gaussian filter (16 taps) along
//   t per column, combine scale*relu(affine)+shift, single f32 write to out.
//   A 16-row halo tile of ysh/ysc (extra gload_lds row block + hacc MFMAs on
//   waves wm==0) makes each block's filter self-contained.
// - Geometry: BM=256(+16 halo) x [3 mats x 64] BN, BK=64, 8 waves 4Mx2N,
//   acc 96+16 regs; grid 512 = 32M x 16N; XCD-ownership remap (FETCH
//   137->44 MB, R7-proven). Swizzle swz(row)=(row&7)<<4 applied on the
//   gload_lds SOURCE and the ds_read side (rule #21 pair).
// Probed and null on this op (16-round session): finer vmcnt depths (2,3),
// coarse phase split, per-phase barrier interleave, 4-wave x 3-block
// occupancy. Remaining gap to the ~57 us ideal is the m201-class
// derived-waits schedule (unreproduced; learn-loop m232 marks it OPEN).
// ---------------------------------------------------------------------------
__global__ __launch_bounds__(512, 2) void gemm_all(
    const unsigned short* __restrict__ xb, const unsigned short* __restrict__ Wt3,
    const float* __restrict__ ba, const float* __restrict__ bsh,
    const float* __restrict__ bsc, float* __restrict__ out)
{
  // staging: sX0 @0 (34816 = 272 rows x 128B), sX1 @34816,
  //          sB0 @69632 (24576 = 3 x 64 x 128B), sB1 @94208  -> 118784 B
  // epilogue union: ysh [64][274] @0, ysc @35072, aff [64][258] @70144
  __shared__ __attribute__((aligned(16))) char lds[118784];
  unsigned short* const sX0 = (unsigned short*)lds;
  unsigned short* const sX1 = (unsigned short*)(lds + 34816);
  unsigned short* const sB0 = (unsigned short*)(lds + 69632);
  unsigned short* const sB1 = (unsigned short*)(lds + 94208);
  unsigned short* const ysh_l = (unsigned short*)lds;
  unsigned short* const ysc_l = (unsigned short*)(lds + 35072);
  unsigned short* const aff_l = (unsigned short*)(lds + 70144);

  const int tid = threadIdx.x;
  const int lane = tid & 63;
  const int wid = tid >> 6;      // 0..7
  const int wm = wid >> 1;       // 0..3 (M quarter: 64 rows)
  const int wn = wid & 1;        // 0..1 (N half: 32 cols)
  const int lr = lane & 15;
  const int lk = lane >> 4;

  // 512 blocks = 32 M x 16 N. XCD-ownership remap (R7-proven).
  const int bid = blockIdx.x;
  const int xcd = bid & 7;
  const int rr_ = bid >> 3;          // 0..63
  const int ntl = rr_ & 15;
  const int mg  = rr_ >> 4;          // 0..3
  const int bm0 = (xcd + (mg << 3)) * 256;
  const int bn0 = ntl * 64;
  const bool first = ((bm0 & 1023) == 0);   // batch boundary above this tile

  f32x4 acc[3][4][2];                // [mat][m][jj] = 96 regs
  f32x4 hacc[2][2];                  // halo rows (wm==0 waves): 16 regs
  const f32x4 z = {0.f, 0.f, 0.f, 0.f};
#pragma unroll
  for (int a = 0; a < 3; ++a)
#pragma unroll
    for (int m = 0; m < 4; ++m)
#pragma unroll
      for (int j = 0; j < 2; ++j) acc[a][m][j] = z;
#pragma unroll
  for (int a = 0; a < 2; ++a)
#pragma unroll
    for (int j = 0; j < 2; ++j) hacc[a][j] = z;

  // stage one K-tile (BK=64): sX rows 0..255 = bm0+row, rows 256..271 = halo
  // (bm0-16..bm0-1; dummy row bm0 when first). All swizzle on global SOURCE.
  auto stage = [&](int k0, unsigned short* dX, unsigned short* dB) {
#pragma unroll
    for (int p = 0; p < 4; ++p) {                 // main X: 4 x 8 KB rounds
      const int po = (p * 512 + tid) * 16;
      const int row = po >> 7;                    // 0..255
      const int lo = po ^ ((row & 7) << 4);
      const int colu = (lo & 127) >> 1;
      const unsigned short* src = xb + (size_t)(bm0 + row) * 1024 + k0 + colu;
      __builtin_amdgcn_global_load_lds(
          (const __attribute__((address_space(1))) void*)src,
          (__attribute__((address_space(3))) void*)(dX + (p * 512 + (wid << 6)) * 8),
          16, 0, 0);
    }
    if (tid < 128) {                              // halo X: waves 0-1 only
      const int po = (2048 + tid) * 16;
      const int row = po >> 7;                    // 256..271
      const int lo = po ^ ((row & 7) << 4);
      const int colu = (lo & 127) >> 1;
      int grow = bm0 - 16 + (row - 256);
      if (first) grow = bm0;                      // dummy; epilogue zeroes halo
      const unsigned short* src = xb + (size_t)grow * 1024 + k0 + colu;
      __builtin_amdgcn_global_load_lds(
          (const __attribute__((address_space(1))) void*)src,
          (__attribute__((address_space(3))) void*)(dX + (2048 + (wid << 6)) * 8),
          16, 0, 0);
    }
#pragma unroll
    for (int mat = 0; mat < 3; ++mat) {           // B: 3 x 8 KB rounds
      const int po = tid * 16;
      const int row = po >> 7;                    // 0..63
      const int lo = po ^ ((row & 7) << 4);
      const int colu = (lo & 127) >> 1;
      const unsigned short* src =
          Wt3 + ((size_t)mat << 20) + (size_t)(bn0 + row) * 1024 + k0 + colu;
      __builtin_amdgcn_global_load_lds(
          (const __attribute__((address_space(1))) void*)src,
          (__attribute__((address_space(3))) void*)(dB + mat * 4096 + (wid << 6) * 8),
          16, 0, 0);
    }
  };
  auto rd = [&](const unsigned short* base, int row, int s) -> bf16x8 {
    const int po = row * 128 + (((s * 32 + lk * 8) * 2) ^ ((row & 7) << 4));
    return *(const bf16x8*)((const char*)base + po);
  };

  stage(0, sX0, sB0);
  unsigned short *sXc = sX0, *sBc = sB0, *sXn = sX1, *sBn = sB1;

  for (int kt = 0; kt < 16; ++kt) {
    if (kt + 1 < 16) stage((kt + 1) * 64, sXn, sBn);   // issue next tile NOW

    // T4 counted wait: tile kt's loads landed; tile kt+1's stay in flight.
    if (kt + 1 < 16) {
      if (wid < 2) asm volatile("s_waitcnt vmcnt(8)" ::: "memory");
      else         asm volatile("s_waitcnt vmcnt(7)" ::: "memory");
    } else {
      asm volatile("s_waitcnt vmcnt(0)" ::: "memory");
    }
    __builtin_amdgcn_s_barrier();                      // tile kt ready (all waves)
    asm volatile("" ::: "memory");                     // no LDS read hoists above

#pragma unroll
    for (int s = 0; s < 2; ++s) {
      bf16x8 ax[4], bb[3][2], hax;
#pragma unroll
      for (int m = 0; m < 4; ++m)
        ax[m] = rd(sXc, wm * 64 + m * 16 + lr, s);
#pragma unroll
      for (int mat = 0; mat < 3; ++mat)
#pragma unroll
        for (int jj = 0; jj < 2; ++jj)
          bb[mat][jj] = rd(sBc + mat * 4096, wn * 32 + jj * 16 + lr, s);
      if (wm == 0) hax = rd(sXc, 256 + lr, s);

      __builtin_amdgcn_s_setprio(1);
#pragma unroll
      for (int m = 0; m < 4; ++m)
#pragma unroll
        for (int mat = 0; mat < 3; ++mat)
#pragma unroll
          for (int jj = 0; jj < 2; ++jj)
            acc[mat][m][jj] = __builtin_amdgcn_mfma_f32_16x16x32_bf16(
                ax[m], bb[mat][jj], acc[mat][m][jj], 0, 0, 0);
      if (wm == 0) {
#pragma unroll
        for (int mat = 1; mat < 3; ++mat)
#pragma unroll
          for (int jj = 0; jj < 2; ++jj)
            hacc[mat - 1][jj] = __builtin_amdgcn_mfma_f32_16x16x32_bf16(
                hax, bb[mat][jj], hacc[mat - 1][jj], 0, 0, 0);
      }
      __builtin_amdgcn_s_setprio(0);
    }

    asm volatile("s_waitcnt lgkmcnt(0)" ::: "memory"); // my slot reads done
    __builtin_amdgcn_s_barrier();                      // slot reusable
    asm volatile("" ::: "memory");                     // stage can't sink above

    unsigned short* t1 = sXc; sXc = sXn; sXn = t1;
    unsigned short* t2 = sBc; sBc = sBn; sBn = t2;
  }

  // ---- epilogue: dump acc -> LDS bf16, Gaussian filter along t, combine ----
  // C/D layout: col=lane&15, row=(lane>>4)*4+reg [m89/m91]
#pragma unroll
  for (int jj = 0; jj < 2; ++jj) {
    const int nn = wn * 32 + jj * 16 + lr;          // 0..63
    const float Ba = ba[bn0 + nn];
#pragma unroll
    for (int m = 0; m < 4; ++m)
#pragma unroll
      for (int q = 0; q < 4; ++q) {
        const int rowL = wm * 64 + m * 16 + lk * 4 + q;   // 0..255
        aff_l[nn * 258 + rowL] = f2bf(fmaxf(acc[0][m][jj][q] + Ba, 0.0f));
        ysh_l[nn * 274 + 15 + rowL] = f2bf(acc[1][m][jj][q]);
        ysc_l[nn * 274 + 15 + rowL] = f2bf(acc[2][m][jj][q]);
      }
    if (wm == 0) {
#pragma unroll
      for (int q = 0; q < 4; ++q) {
        const int hr = lk * 4 + q;          // 0..15 <-> global bm0-16+hr
        if (hr > 0) {                       // entries 0..14 = bm0-15..bm0-1
          ysh_l[nn * 274 + hr - 1] = f2bf(hacc[0][jj][q]);
          ysc_l[nn * 274 + hr - 1] = f2bf(hacc[1][jj][q]);
        }
      }
    }
  }
  __syncthreads();
  if (first) {     // batch start: halo is zeros
    for (int i = tid; i < 64 * 15; i += 512) {
      const int nn = i / 15, rw = i % 15;
      ysh_l[nn * 274 + rw] = 0;
      ysc_l[nn * 274 + rw] = 0;
    }
  }
  __syncthreads();

  // filter + combine: thread owns (col nn, 32 rows)
  {
    const int nn = tid & 63;
    const int t0 = (tid >> 6) * 32;                 // 0..224
    float g[16];
#pragma unroll
    for (int k = 0; k < 16; ++k) g[k] = __expf(-(float)(k * k) * 0.125f);
    float nfull = 0.f;
#pragma unroll
    for (int k = 0; k < 16; ++k) nfull += g[k];
    const float invf = 1.0f / nfull;
    const float bs = bsh[bn0 + nn];
    const float bc = bsc[bn0 + nn];

    float psh[15], psc[15];
#pragma unroll
    for (int i = 0; i < 15; ++i) {                  // rows t0-15..t0-1
      psh[i] = bf2f(ysh_l[nn * 274 + t0 + i]);
      psc[i] = bf2f(ysc_l[nn * 274 + t0 + i]);
    }

    for (int c = 0; c < 2; ++c) {                   // 2 chunks of 16 rows
      const int T = t0 + c * 16;
      float csh[16], csc[16], av[16];
#pragma unroll
      for (int u = 0; u < 16; ++u) {
        csh[u] = bf2f(ysh_l[nn * 274 + 15 + T + u]);
        csc[u] = bf2f(ysc_l[nn * 274 + 15 + T + u]);
        av[u]  = bf2f(aff_l[nn * 258 + T + u]);
      }
#pragma unroll
      for (int u = 0; u < 16; ++u) {
        float fs = 0.f, fc = 0.f;
#pragma unroll
        for (int k = 0; k < 16; ++k) {
          const int d = u - k;
          const float vs = (d >= 0) ? csh[d] : psh[15 + d];
          const float vc = (d >= 0) ? csc[d] : psc[15 + d];
          fs = fmaf(g[k], vs, fs);
          fc = fmaf(g[k], vc, fc);
        }
        float inv = invf;
        if (first && (T + u) < 15) {                // partial norm at batch start
          float sum = 0.f;
#pragma unroll
          for (int k = 0; k < 16; ++k) sum += (k <= T + u) ? g[k] : 0.f;
          inv = 1.0f / sum;
        }
        out[(size_t)(bm0 + T + u) * 1024 + bn0 + nn] =
            (fc * inv + bc) * av[u] + (fs * inv + bs);
      }
#pragma unroll
      for (int i = 0; i < 15; ++i) { psh[i] = csh[i + 1]; psc[i] = csc[i + 1]; }
    }
  }
}

// ---------------------------------------------------------------------------
// Workspace layout (22 MiB, proven safe):
//   xb  : ws + 0        16 MiB (x as bf16)
//   Wt3 : ws + 16 MiB    6 MiB (concat Wa^T|Wshift^T|Wscale^T, bf16)
// d_out is written ONCE by gemm_all (final f32).
// ---------------------------------------------------------------------------
extern "C" void kernel_launch(void* const* d_in, const int* in_sizes, int n_in,
                              void* d_out, int out_size, void* d_ws, size_t ws_size,
                              hipStream_t stream) {
  const float* x   = (const float*)d_in[0];
  const float* Wa  = (const float*)d_in[1];
  const float* ba  = (const float*)d_in[2];
  const float* Wsh = (const float*)d_in[3];
  const float* bsh = (const float*)d_in[4];
  const float* Wsc = (const float*)d_in[5];
  const float* bsc = (const float*)d_in[6];
  float* out = (float*)d_out;

  char* ws = (char*)d_ws;
  unsigned short* xb  = (unsigned short*)(ws);
  unsigned short* Wt3 = (unsigned short*)(ws + (16u << 20));

  hipLaunchKernelGGL(prep, dim3(4096 + 768), dim3(256), 0, stream,
                     x, xb, Wa, Wsh, Wsc, Wt3);
  hipLaunchKernelGGL(gemm_all, dim3(512), dim3(512), 0, stream,
                     xb, Wt3, ba, bsh, bsc, out);
}